// Round 11
// baseline (301.660 us; speedup 1.0000x reference)
//
#include <hip/hip_runtime.h>
#include <math.h>

// ---------------------------------------------------------------------------
// TrafficGNN: 2-layer GCN + BN + ReLU + log_softmax.
// Round 11: column-major 8-way split counters cnt[(i&7)*n + col] (copies a
// full 400KB apart -> 8x distinct cache lines at the atomic unit). R8's
// failed split was row-major (32B apart, SAME line) — invalid experiment.
// Scan runs over 8n buckets in node-major order via permuted reads; CSR
// segments stay contiguous per node.
// ---------------------------------------------------------------------------

typedef unsigned int   uint;
typedef unsigned short ushort;
typedef __bf16 bf16x8 __attribute__((ext_vector_type(8)));
typedef float  f32x4  __attribute__((ext_vector_type(4)));

union U16 { uint4 u; bf16x8 b; };

__device__ __forceinline__ void atomAddF(float* p, float v) {
    __hip_atomic_fetch_add(p, v, __ATOMIC_RELAXED, __HIP_MEMORY_SCOPE_AGENT);
}

// float -> bf16 (round to nearest even)
__device__ __forceinline__ ushort f2bf(float f) {
    uint u = __float_as_uint(f);
    u += 0x7FFFu + ((u >> 16) & 1u);
    return (ushort)(u >> 16);
}
__device__ __forceinline__ float bf2f(ushort h) {
    return __uint_as_float(((uint)h) << 16);
}
__device__ __forceinline__ uint pack2(float f0, float f1) {
    return (uint)f2bf(f0) | ((uint)f2bf(f1) << 16);
}

// zero 8n split counters + BN accumulators
__global__ void k_init(int* __restrict__ cnt, float* __restrict__ bn, int m) {
    int i = blockIdx.x * 256 + threadIdx.x;
    if (i < m) cnt[i] = 0;
    if (i < 256) bn[i] = 0.0f;   // bn[0..127]=sum, bn[128..255]=sumsq
}

// rank[i] = slot within (target, copy) bucket; copy stride = n (line-spread)
__global__ void k_cnt(const int* __restrict__ col, int* __restrict__ cnt,
                      int* __restrict__ rank, int e, int n) {
    int i = blockIdx.x * 256 + threadIdx.x;
    if (i < e) rank[i] = atomicAdd(&cnt[(i & 7) * n + col[i]], 1);
}

// ---- exclusive scan over 8n buckets in node-major order ----
// bucket b = node*8 + copy; value read from cnt[copy*n + node].

__global__ __launch_bounds__(256)
void k_scanA(const int* __restrict__ cnt, int* __restrict__ bsum,
             int m, int n) {
    __shared__ int ls[256];
    int base = blockIdx.x * 1024 + threadIdx.x * 4;
    int s = 0;
#pragma unroll
    for (int k = 0; k < 4; ++k) {
        int b = base + k;
        if (b < m) s += cnt[(b & 7) * n + (b >> 3)];
    }
    ls[threadIdx.x] = s;
    __syncthreads();
    for (int d = 128; d > 0; d >>= 1) {
        if (threadIdx.x < d) ls[threadIdx.x] += ls[threadIdx.x + d];
        __syncthreads();
    }
    if (threadIdx.x == 0) bsum[blockIdx.x] = ls[0];
}

// parallel exclusive scan of block sums (nblk <= 1024); also ptr[m] = total
__global__ __launch_bounds__(1024)
void k_scanB(int* __restrict__ bsum, int* __restrict__ ptr, int nblk, int m) {
    __shared__ int ls[1024];
    int t = threadIdx.x;
    int v = (t < nblk) ? bsum[t] : 0;
    ls[t] = v;
    __syncthreads();
    for (int d = 1; d < 1024; d <<= 1) {
        int mine = ls[t];
        int up   = (t >= d) ? ls[t - d] : 0;
        __syncthreads();
        ls[t] = mine + up;
        __syncthreads();
    }
    if (t < nblk) bsum[t] = ls[t] - v;   // exclusive
    if (t == 0) ptr[m] = ls[1023];       // total
}

__global__ __launch_bounds__(256)
void k_scanC(const int* __restrict__ cnt, const int* __restrict__ bsum,
             int* __restrict__ ptr, int m, int n) {
    __shared__ int ls[256];
    int base = blockIdx.x * 1024 + threadIdx.x * 4;
    int v[4];
#pragma unroll
    for (int k = 0; k < 4; ++k) {
        int b = base + k;
        v[k] = (b < m) ? cnt[(b & 7) * n + (b >> 3)] : 0;
    }
    int t = v[0] + v[1] + v[2] + v[3];
    ls[threadIdx.x] = t;
    __syncthreads();
    for (int d = 1; d < 256; d <<= 1) {
        int mine = ls[threadIdx.x];
        int up   = (threadIdx.x >= d) ? ls[threadIdx.x - d] : 0;
        __syncthreads();
        ls[threadIdx.x] = mine + up;
        __syncthreads();
    }
    int off = bsum[blockIdx.x] + ls[threadIdx.x] - t;   // exclusive
    int pf = 0;
#pragma unroll
    for (int k = 0; k < 4; ++k) {
        int b = base + k;
        if (b < m) ptr[b] = off + pf;
        pf += v[k];
    }
}

// atomic-free CSR fill: slot = ptr[tgt*8 + copy] + rank; store (src, raw ew)
__global__ void k_fill(const int* __restrict__ row, const int* __restrict__ col,
                       const float* __restrict__ ew, const int* __restrict__ rank,
                       const int* __restrict__ ptr, int2* __restrict__ csr, int e) {
    int i = blockIdx.x * 256 + threadIdx.x;
    if (i < e) {
        int pos = ptr[(col[i] << 3) + (i & 7)] + rank[i];
        int2 pr;
        pr.x = row[i];
        pr.y = __float_as_int(ew[i]);
        csr[pos] = pr;
    }
}

// dinv[i] = rsqrt(1 + sum of raw ew over node segment)   (16 lanes per node)
__global__ __launch_bounds__(256)
void k_degsum(const int* __restrict__ ptr, const int2* __restrict__ csr,
              float* __restrict__ dinv, int n) {
    int lane = threadIdx.x & 15;
    int node = (blockIdx.x * 256 + threadIdx.x) >> 4;
    if (node >= n) return;
    int p0 = ptr[node << 3], p1 = ptr[(node << 3) + 8];
    float s = 0.f;
    for (int j = p0 + lane; j < p1; j += 16) s += __int_as_float(csr[j].y);
#pragma unroll
    for (int off = 8; off > 0; off >>= 1) s += __shfl_xor(s, off, 16);
    if (lane == 0) dinv[node] = rsqrtf(1.0f + s);
}

// W[128][M] f32 row-major -> bf16 fragment order (one thread per fragment)
__global__ void k_wfrag(const float* __restrict__ W, uint4* __restrict__ Wf, int M) {
    int t = blockIdx.x * 256 + threadIdx.x;
    if (t >= M * 16) return;
    int l  = t & 63;
    int ks = (t >> 6) & 3;
    int nt = t >> 8;
    int kbase = ks * 32 + (l >> 4) * 8;
    int colj  = nt * 16 + (l & 15);
    float v[8];
#pragma unroll
    for (int j = 0; j < 8; ++j) v[j] = W[(kbase + j) * M + colj];
    uint4 o;
    o.x = pack2(v[0], v[1]);
    o.y = pack2(v[2], v[3]);
    o.z = pack2(v[4], v[5]);
    o.w = pack2(v[6], v[7]);
    Wf[t] = o;
}

// H[n,M](bf16) = X'[n,128] @ W[128,M] via 16x16x32 bf16 MFMA.
// BN=false: X is f32.  BN=true: X is bf16, X' = relu(X*scale+shift).
template<int M, bool BN>
__global__ __launch_bounds__(256)
void k_mfma(const void* __restrict__ Xv, const uint4* __restrict__ Wf,
            const float* __restrict__ scale, const float* __restrict__ shift,
            ushort* __restrict__ H, int n)
{
    constexpr int NT = M / 16;
    const int l = threadIdx.x & 63;
    const int w = threadIdx.x >> 6;
    const int rowbase = blockIdx.x * 64 + w * 16;
    const int arow = rowbase + (l & 15);
    const bool rv = arow < n;
    const int koff = (l >> 4) * 8;

    f32x4 acc[NT];
#pragma unroll
    for (int t = 0; t < NT; ++t) acc[t] = (f32x4){0.f, 0.f, 0.f, 0.f};

#pragma unroll
    for (int ks = 0; ks < 4; ++ks) {
        U16 ua;
        if (BN) {
            const ushort* xr = (const ushort*)Xv + (size_t)arow * 128 + koff;
            U16 xa; xa.u = make_uint4(0, 0, 0, 0);
            if (rv) xa.u = *(const uint4*)(xr + ks * 32);
            int k0 = ks * 32 + koff;
            float4 sc0 = *(const float4*)(scale + k0);
            float4 sc1 = *(const float4*)(scale + k0 + 4);
            float4 sh0 = *(const float4*)(shift + k0);
            float4 sh1 = *(const float4*)(shift + k0 + 4);
            float a[8];
            a[0] = fmaxf(0.f, fmaf(bf2f((ushort)(xa.u.x)),       sc0.x, sh0.x));
            a[1] = fmaxf(0.f, fmaf(bf2f((ushort)(xa.u.x >> 16)), sc0.y, sh0.y));
            a[2] = fmaxf(0.f, fmaf(bf2f((ushort)(xa.u.y)),       sc0.z, sh0.z));
            a[3] = fmaxf(0.f, fmaf(bf2f((ushort)(xa.u.y >> 16)), sc0.w, sh0.w));
            a[4] = fmaxf(0.f, fmaf(bf2f((ushort)(xa.u.z)),       sc1.x, sh1.x));
            a[5] = fmaxf(0.f, fmaf(bf2f((ushort)(xa.u.z >> 16)), sc1.y, sh1.y));
            a[6] = fmaxf(0.f, fmaf(bf2f((ushort)(xa.u.w)),       sc1.z, sh1.z));
            a[7] = fmaxf(0.f, fmaf(bf2f((ushort)(xa.u.w >> 16)), sc1.w, sh1.w));
            ua.u.x = pack2(a[0], a[1]);
            ua.u.y = pack2(a[2], a[3]);
            ua.u.z = pack2(a[4], a[5]);
            ua.u.w = pack2(a[6], a[7]);
        } else {
            const float* xr = (const float*)Xv + (size_t)arow * 128 + koff;
            float4 a0 = make_float4(0.f, 0.f, 0.f, 0.f);
            float4 a1 = a0;
            if (rv) {
                a0 = *(const float4*)(xr + ks * 32);
                a1 = *(const float4*)(xr + ks * 32 + 4);
            }
            ua.u.x = pack2(a0.x, a0.y);
            ua.u.y = pack2(a0.z, a0.w);
            ua.u.z = pack2(a1.x, a1.y);
            ua.u.w = pack2(a1.z, a1.w);
        }
#pragma unroll
        for (int nt = 0; nt < NT; ++nt) {
            U16 ub;
            ub.u = Wf[(nt * 4 + ks) * 64 + l];
            acc[nt] = __builtin_amdgcn_mfma_f32_16x16x32_bf16(ua.b, ub.b, acc[nt], 0, 0, 0);
        }
    }

    // epilogue: transpose through padded LDS, then coalesced 16B stores.
    __shared__ __align__(16) ushort lds[4][16][M + 8];
#pragma unroll
    for (int nt = 0; nt < NT; ++nt)
#pragma unroll
        for (int r = 0; r < 4; ++r)
            lds[w][(l >> 4) * 4 + r][nt * 16 + (l & 15)] = f2bf(acc[nt][r]);
    __syncthreads();

    constexpr int LPR = M / 8;
    constexpr int RPP = 64 / LPR;
#pragma unroll
    for (int it = 0; it < 16 / RPP; ++it) {
        int rl = it * RPP + (l / LPR);
        int gr = rowbase + rl;
        if (gr < n)
            *(uint4*)(H + (size_t)gr * M + (l % LPR) * 8) =
                *(const uint4*)&lds[w][rl][(l % LPR) * 8];
    }
}

// layer-1 gather, 16-lane group per node (4 nodes/wave):
// out bf16 = b1 + h[i]*dinv^2 + sum h[src]*(ew*dinv[src]*di); h bf16[n][128]
__global__ __launch_bounds__(256)
void k_gather1(const int* __restrict__ ptr, const int2* __restrict__ csr,
               const ushort* __restrict__ h, const float* __restrict__ dinv,
               const float* __restrict__ bias, ushort* __restrict__ out, int n)
{
    int lane = threadIdx.x & 15;
    int node = (blockIdx.x * 256 + threadIdx.x) >> 4;
    if (node >= n) return;
    int p0 = ptr[node << 3], p1 = ptr[(node << 3) + 8];
    float di = dinv[node];
    float s  = di * di;

    U16 hv; hv.u = *(const uint4*)(h + (size_t)node * 128 + lane * 8);
    float4 b0 = *(const float4*)(bias + lane * 8);
    float4 b1v = *(const float4*)(bias + lane * 8 + 4);
    float acc[8];
    acc[0] = fmaf(bf2f((ushort)(hv.u.x)),       s, b0.x);
    acc[1] = fmaf(bf2f((ushort)(hv.u.x >> 16)), s, b0.y);
    acc[2] = fmaf(bf2f((ushort)(hv.u.y)),       s, b0.z);
    acc[3] = fmaf(bf2f((ushort)(hv.u.y >> 16)), s, b0.w);
    acc[4] = fmaf(bf2f((ushort)(hv.u.z)),       s, b1v.x);
    acc[5] = fmaf(bf2f((ushort)(hv.u.z >> 16)), s, b1v.y);
    acc[6] = fmaf(bf2f((ushort)(hv.u.w)),       s, b1v.z);
    acc[7] = fmaf(bf2f((ushort)(hv.u.w >> 16)), s, b1v.w);

#pragma unroll 4
    for (int j = p0; j < p1; ++j) {
        int2 pr = csr[j];
        float w = __int_as_float(pr.y) * di * dinv[pr.x];
        U16 v; v.u = *(const uint4*)(h + (size_t)pr.x * 128 + lane * 8);
        acc[0] = fmaf(bf2f((ushort)(v.u.x)),       w, acc[0]);
        acc[1] = fmaf(bf2f((ushort)(v.u.x >> 16)), w, acc[1]);
        acc[2] = fmaf(bf2f((ushort)(v.u.y)),       w, acc[2]);
        acc[3] = fmaf(bf2f((ushort)(v.u.y >> 16)), w, acc[3]);
        acc[4] = fmaf(bf2f((ushort)(v.u.z)),       w, acc[4]);
        acc[5] = fmaf(bf2f((ushort)(v.u.z >> 16)), w, acc[5]);
        acc[6] = fmaf(bf2f((ushort)(v.u.w)),       w, acc[6]);
        acc[7] = fmaf(bf2f((ushort)(v.u.w >> 16)), w, acc[7]);
    }

    U16 o;
    o.u.x = pack2(acc[0], acc[1]);
    o.u.y = pack2(acc[2], acc[3]);
    o.u.z = pack2(acc[4], acc[5]);
    o.u.w = pack2(acc[6], acc[7]);
    *(uint4*)(out + (size_t)node * 128 + lane * 8) = o.u;
}

// layer-2 gather + fused log_softmax, 8-lane group per node (8 nodes/wave)
__global__ __launch_bounds__(256)
void k_gather2(const int* __restrict__ ptr, const int2* __restrict__ csr,
               const ushort* __restrict__ h, const float* __restrict__ dinv,
               const float* __restrict__ bias, float* __restrict__ out, int n)
{
    int lane = threadIdx.x & 7;
    int node = (blockIdx.x * 256 + threadIdx.x) >> 3;
    if (node >= n) return;
    int p0 = ptr[node << 3], p1 = ptr[(node << 3) + 8];
    float di = dinv[node];
    float s  = di * di;

    U16 hv; hv.u = *(const uint4*)(h + (size_t)node * 64 + lane * 8);
    float4 b0 = *(const float4*)(bias + lane * 8);
    float4 b1v = *(const float4*)(bias + lane * 8 + 4);
    float acc[8];
    acc[0] = fmaf(bf2f((ushort)(hv.u.x)),       s, b0.x);
    acc[1] = fmaf(bf2f((ushort)(hv.u.x >> 16)), s, b0.y);
    acc[2] = fmaf(bf2f((ushort)(hv.u.y)),       s, b0.z);
    acc[3] = fmaf(bf2f((ushort)(hv.u.y >> 16)), s, b0.w);
    acc[4] = fmaf(bf2f((ushort)(hv.u.z)),       s, b1v.x);
    acc[5] = fmaf(bf2f((ushort)(hv.u.z >> 16)), s, b1v.y);
    acc[6] = fmaf(bf2f((ushort)(hv.u.w)),       s, b1v.z);
    acc[7] = fmaf(bf2f((ushort)(hv.u.w >> 16)), s, b1v.w);

#pragma unroll 4
    for (int j = p0; j < p1; ++j) {
        int2 pr = csr[j];
        float w = __int_as_float(pr.y) * di * dinv[pr.x];
        U16 v; v.u = *(const uint4*)(h + (size_t)pr.x * 64 + lane * 8);
        acc[0] = fmaf(bf2f((ushort)(v.u.x)),       w, acc[0]);
        acc[1] = fmaf(bf2f((ushort)(v.u.x >> 16)), w, acc[1]);
        acc[2] = fmaf(bf2f((ushort)(v.u.y)),       w, acc[2]);
        acc[3] = fmaf(bf2f((ushort)(v.u.y >> 16)), w, acc[3]);
        acc[4] = fmaf(bf2f((ushort)(v.u.z)),       w, acc[4]);
        acc[5] = fmaf(bf2f((ushort)(v.u.z >> 16)), w, acc[5]);
        acc[6] = fmaf(bf2f((ushort)(v.u.w)),       w, acc[6]);
        acc[7] = fmaf(bf2f((ushort)(v.u.w >> 16)), w, acc[7]);
    }

    // log_softmax over the group's 64 features (8 in-lane + 8 lanes)
    float m = acc[0];
#pragma unroll
    for (int k = 1; k < 8; ++k) m = fmaxf(m, acc[k]);
#pragma unroll
    for (int off = 1; off < 8; off <<= 1) m = fmaxf(m, __shfl_xor(m, off, 64));
    float sum = 0.f;
#pragma unroll
    for (int k = 0; k < 8; ++k) sum += expf(acc[k] - m);
#pragma unroll
    for (int off = 1; off < 8; off <<= 1) sum += __shfl_xor(sum, off, 64);
    float lse = m + logf(sum);

    float* orow = out + (size_t)node * 64 + lane * 8;
    *(float4*)(orow)     = make_float4(acc[0] - lse, acc[1] - lse, acc[2] - lse, acc[3] - lse);
    *(float4*)(orow + 4) = make_float4(acc[4] - lse, acc[5] - lse, acc[6] - lse, acc[7] - lse);
}

// per-feature sum & sumsq over nodes; a is bf16[n][128]
__global__ __launch_bounds__(256)
void k_bn_stats(const ushort* __restrict__ a, float* __restrict__ sums,
                float* __restrict__ sumsq, int n)
{
    int fp = threadIdx.x & 63;       // feature pair
    int rg = threadIdx.x >> 6;       // row group 0..3
    float s0 = 0.f, q0 = 0.f, s1 = 0.f, q1 = 0.f;
    for (int r = blockIdx.x * 4 + rg; r < n; r += gridDim.x * 4) {
        uint v = *(const uint*)(a + (size_t)r * 128 + fp * 2);
        float x0 = bf2f((ushort)v), x1 = bf2f((ushort)(v >> 16));
        s0 += x0; q0 += x0 * x0;
        s1 += x1; q1 += x1 * x1;
    }
    __shared__ float l0[256], l1[256], l2[256], l3[256];
    l0[threadIdx.x] = s0; l1[threadIdx.x] = q0;
    l2[threadIdx.x] = s1; l3[threadIdx.x] = q1;
    __syncthreads();
    if (rg == 0) {
        float S0 = l0[fp] + l0[fp + 64] + l0[fp + 128] + l0[fp + 192];
        float Q0 = l1[fp] + l1[fp + 64] + l1[fp + 128] + l1[fp + 192];
        float S1 = l2[fp] + l2[fp + 64] + l2[fp + 128] + l2[fp + 192];
        float Q1 = l3[fp] + l3[fp + 64] + l3[fp + 128] + l3[fp + 192];
        atomAddF(&sums[fp * 2],      S0);
        atomAddF(&sumsq[fp * 2],     Q0);
        atomAddF(&sums[fp * 2 + 1],  S1);
        atomAddF(&sumsq[fp * 2 + 1], Q1);
    }
}

__global__ void k_bn_final(const float* __restrict__ bn, const float* __restrict__ gamma,
                           const float* __restrict__ beta, float* __restrict__ scale,
                           float* __restrict__ shift, int n)
{
    int f = threadIdx.x;
    if (f < 128) {
        float inv_n = 1.0f / (float)n;
        float mu  = bn[f] * inv_n;
        float var = bn[128 + f] * inv_n - mu * mu;
        float rstd = rsqrtf(var + 1e-5f);
        float sc = gamma[f] * rstd;
        scale[f] = sc;
        shift[f] = beta[f] - mu * sc;
    }
}

extern "C" void kernel_launch(void* const* d_in, const int* in_sizes, int n_in,
                              void* d_out, int out_size, void* d_ws, size_t ws_size,
                              hipStream_t stream)
{
    const float* x     = (const float*)d_in[0];
    const int*   ei    = (const int*)  d_in[1];
    const float* ew    = (const float*)d_in[2];
    const float* W1    = (const float*)d_in[3];
    const float* b1    = (const float*)d_in[4];
    const float* gamma = (const float*)d_in[5];
    const float* beta  = (const float*)d_in[6];
    const float* W2    = (const float*)d_in[7];
    const float* b2    = (const float*)d_in[8];

    const int n = in_sizes[0] / 128;   // 100000
    const int e = in_sizes[2];         // 1600000
    const int* row = ei;               // edge_index[0]  (source)
    const int* col = ei + e;           // edge_index[1]  (target)
    const int m = n * 8;               // bucket count

    // workspace layout (4-byte units):
    // dinv[n] | h1 bf16[n*128] (h2 aliases) | agg1 bf16[n*128] (rank aliases
    // only in f32 slot below) | bn[256] | scale[128] | shift[128] |
    // cnt[8n] (copy-major) | ptr[8n+1] (node-major) | bsum[1024] |
    // w1f | w2f | csr[e] (int2) | rank[e]
    float* ws    = (float*)d_ws;
    size_t off   = 0;
    float* dinv  = ws + off; off += n;
    ushort* h1   = (ushort*)(ws + off); off += (size_t)n * 64;  // n*128 bf16
    ushort* agg1 = (ushort*)(ws + off); off += (size_t)n * 64;  // n*128 bf16
    float* bn    = ws + off; off += 256;
    float* scale = ws + off; off += 128;
    float* shift = ws + off; off += 128;
    int*   cnt   = (int*)(ws + off); off += (size_t)m;
    int*   ptr   = (int*)(ws + off); off += (size_t)(m + 1);
    int*   bsum  = (int*)(ws + off); off += 1024;
    off = (off + 3) & ~(size_t)3;       // 16-byte align for uint4
    uint4* w1f   = (uint4*)(ws + off); off += 8192;  // 128*128 bf16 = 2048 uint4
    uint4* w2f   = (uint4*)(ws + off); off += 4096;  // 128*64  bf16 = 1024 uint4
    int2*  csr   = (int2*)(ws + off); off += (size_t)e * 2;
    int*   rank  = (int*)(ws + off);    // dedicated (agg1 is bf16-packed now)
    ushort* h2   = h1;                  // h1 dead after k_gather1
    float* outp  = (float*)d_out;

    const int nb_m = (m + 255) / 256;
    const int nb_e = (e + 255) / 256;
    const int nb_qpn = (n + 15) / 16;   // 16-lane-group-per-node
    const int nb_opn = (n + 31) / 32;   // 8-lane-group-per-node
    const int nb_mf  = (n + 63) / 64;   // MFMA gemm: 64 rows/block
    const int nblk_scan = (m + 1023) / 1024;   // 782 <= 1024

    // W fragment swizzle (no deps)
    k_wfrag<<<8, 256, 0, stream>>>(W1, w1f, 128);
    k_wfrag<<<4, 256, 0, stream>>>(W2, w2f, 64);

    // CSR build: count(+rank, line-spread split) -> scan -> fill -> degsum
    k_init<<<nb_m, 256, 0, stream>>>(cnt, bn, m);
    k_cnt<<<nb_e, 256, 0, stream>>>(col, cnt, rank, e, n);
    k_scanA<<<nblk_scan, 256, 0, stream>>>(cnt, bsum, m, n);
    k_scanB<<<1, 1024, 0, stream>>>(bsum, ptr, nblk_scan, m);
    k_scanC<<<nblk_scan, 256, 0, stream>>>(cnt, bsum, ptr, m, n);
    k_fill<<<nb_e, 256, 0, stream>>>(row, col, ew, rank, ptr, csr, e);
    k_degsum<<<nb_qpn, 256, 0, stream>>>(ptr, csr, dinv, n);

    // ---- layer 1: h1 = x @ W1 (bf16, MFMA) ; agg1 = gather(h1) + b1 (bf16) ----
    k_mfma<128, false><<<nb_mf, 256, 0, stream>>>(x, w1f, nullptr, nullptr, h1, n);
    k_gather1<<<nb_qpn, 256, 0, stream>>>(ptr, csr, h1, dinv, b1, agg1, n);

    // ---- batchnorm stats -> scale/shift ----
    k_bn_stats<<<256, 256, 0, stream>>>(agg1, bn, bn + 128, n);
    k_bn_final<<<1, 128, 0, stream>>>(bn, gamma, beta, scale, shift, n);

    // ---- layer 2: h2 = relu(bn(agg1)) @ W2 (bf16, MFMA) ; out + lsm ----
    k_mfma<64, true><<<nb_mf, 256, 0, stream>>>(agg1, w2f, scale, shift, h2, n);
    k_gather2<<<nb_opn, 256, 0, stream>>>(ptr, csr, h2, dinv, b2, outp, n);
}

// Round 12
// 252.990 us; speedup vs baseline: 1.1924x; 1.1924x over previous
//
#include <hip/hip_runtime.h>
#include <math.h>

// ---------------------------------------------------------------------------
// TrafficGNN: 2-layer GCN + BN + ReLU + log_softmax.
// Round 12: atomic-free CSR build (global scattered atomics run at a fixed
// ~24 G/s regardless of contention — R8/R11 experiments). Two-level LDS
// bucketing: P1 histogram by col>>9 -> scan -> P3 bucket scatter (LDS ranks)
// -> P4 per-bucket build (LDS counts/scan/ranks + fused degsum->dinv).
// Downstream (MFMA GEMMs, bf16 gathers, fused BN/lsm) = R10 structure.
// ---------------------------------------------------------------------------

typedef unsigned int   uint;
typedef unsigned short ushort;
typedef __bf16 bf16x8 __attribute__((ext_vector_type(8)));
typedef float  f32x4  __attribute__((ext_vector_type(4)));

#define EPB  4096      // edges per P1/P3 block
#define BSH  9         // 512 nodes per bucket

union U16 { uint4 u; bf16x8 b; };

__device__ __forceinline__ void atomAddF(float* p, float v) {
    __hip_atomic_fetch_add(p, v, __ATOMIC_RELAXED, __HIP_MEMORY_SCOPE_AGENT);
}

__device__ __forceinline__ ushort f2bf(float f) {
    uint u = __float_as_uint(f);
    u += 0x7FFFu + ((u >> 16) & 1u);
    return (ushort)(u >> 16);
}
__device__ __forceinline__ float bf2f(ushort h) {
    return __uint_as_float(((uint)h) << 16);
}
__device__ __forceinline__ uint pack2(float f0, float f1) {
    return (uint)f2bf(f0) | ((uint)f2bf(f1) << 16);
}

// ---- P1: per-block LDS histogram over buckets (col>>BSH) ----
__global__ __launch_bounds__(256)
void k_p1(const int* __restrict__ col, int* __restrict__ ghist,
          int e, int PB) {
    __shared__ int lh[256];
    lh[threadIdx.x] = 0;
    __syncthreads();
    int base = blockIdx.x * EPB;
    int end  = base + EPB; if (end > e) end = e;
    for (int j = base + threadIdx.x; j < end; j += 256)
        atomicAdd(&lh[col[j] >> BSH], 1);
    __syncthreads();
    // bucket-major layout: ghist[bucket*PB + blk]
    ghist[threadIdx.x * PB + blockIdx.x] = lh[threadIdx.x];
}

// ---- linear exclusive scan over tot = NB*PB elements ----
__global__ __launch_bounds__(256)
void k_scanA(const int* __restrict__ v, int* __restrict__ bsum, int tot) {
    __shared__ int ls[256];
    int base = blockIdx.x * 1024 + threadIdx.x * 4;
    int s = 0;
#pragma unroll
    for (int k = 0; k < 4; ++k) { int i = base + k; if (i < tot) s += v[i]; }
    ls[threadIdx.x] = s;
    __syncthreads();
    for (int d = 128; d > 0; d >>= 1) {
        if (threadIdx.x < d) ls[threadIdx.x] += ls[threadIdx.x + d];
        __syncthreads();
    }
    if (threadIdx.x == 0) bsum[blockIdx.x] = ls[0];
}

// parallel exclusive scan of block sums; also zeroes BN accumulators
__global__ __launch_bounds__(1024)
void k_scanB(int* __restrict__ bsum, float* __restrict__ bn, int nblk) {
    __shared__ int ls[1024];
    int t = threadIdx.x;
    if (t < 256) bn[t] = 0.0f;
    int v = (t < nblk) ? bsum[t] : 0;
    ls[t] = v;
    __syncthreads();
    for (int d = 1; d < 1024; d <<= 1) {
        int mine = ls[t];
        int up   = (t >= d) ? ls[t - d] : 0;
        __syncthreads();
        ls[t] = mine + up;
        __syncthreads();
    }
    if (t < nblk) bsum[t] = ls[t] - v;   // exclusive
}

__global__ __launch_bounds__(256)
void k_scanC(const int* __restrict__ v, const int* __restrict__ bsum,
             int* __restrict__ gout, int tot) {
    __shared__ int ls[256];
    int base = blockIdx.x * 1024 + threadIdx.x * 4;
    int w[4];
#pragma unroll
    for (int k = 0; k < 4; ++k) { int i = base + k; w[k] = (i < tot) ? v[i] : 0; }
    int t = w[0] + w[1] + w[2] + w[3];
    ls[threadIdx.x] = t;
    __syncthreads();
    for (int d = 1; d < 256; d <<= 1) {
        int mine = ls[threadIdx.x];
        int up   = (threadIdx.x >= d) ? ls[threadIdx.x - d] : 0;
        __syncthreads();
        ls[threadIdx.x] = mine + up;
        __syncthreads();
    }
    int off = bsum[blockIdx.x] + ls[threadIdx.x] - t;   // exclusive
    int pf = 0;
#pragma unroll
    for (int k = 0; k < 4; ++k) {
        int i = base + k;
        if (i < tot) gout[i] = off + pf;
        pf += w[k];
    }
}

// ---- P3: scatter edges into bucket-partitioned staging (LDS ranks) ----
__global__ __launch_bounds__(256)
void k_p3(const int* __restrict__ row, const int* __restrict__ col,
          const float* __restrict__ ew, const int* __restrict__ goff,
          int2* __restrict__ ebuf, ushort* __restrict__ ecol,
          int e, int PB) {
    __shared__ int cur[256];
    cur[threadIdx.x] = 0;
    __syncthreads();
    int blk  = blockIdx.x;
    int base = blk * EPB;
    int end  = base + EPB; if (end > e) end = e;
    for (int j = base + threadIdx.x; j < end; j += 256) {
        int c = col[j];
        int b = c >> BSH;
        int r = atomicAdd(&cur[b], 1);
        int pos = goff[b * PB + blk] + r;
        ebuf[pos] = make_int2(row[j], __float_as_int(ew[j]));
        ecol[pos] = (ushort)(c & ((1 << BSH) - 1));
    }
}

// ---- P4: per-bucket CSR build + dinv (one block of 512 per bucket) ----
__global__ __launch_bounds__(512)
void k_p4(const int* __restrict__ goff, const int2* __restrict__ ebuf,
          const ushort* __restrict__ ecol, int2* __restrict__ csr,
          int* __restrict__ ptr, float* __restrict__ dinv,
          int n, int e, int PB, int NB) {
    __shared__ int   cnt[512];
    __shared__ float fs[512];
    __shared__ int   cur2[512];
    __shared__ int   sc[512];
    int tid = threadIdx.x;
    int b   = blockIdx.x;
    int bstart = goff[b * PB];
    int bend   = (b == NB - 1) ? e : goff[(b + 1) * PB];

    cnt[tid] = 0; fs[tid] = 0.f; cur2[tid] = 0;
    __syncthreads();

    // pass 1: per-node counts + edge-weight sums
    for (int j = bstart + tid; j < bend; j += 512) {
        int c = (int)ecol[j];
        atomicAdd(&cnt[c], 1);
        atomicAdd(&fs[c], __int_as_float(ebuf[j].y));
    }
    __syncthreads();

    // exclusive scan of cnt[512]
    int v = cnt[tid];
    sc[tid] = v;
    __syncthreads();
    for (int d = 1; d < 512; d <<= 1) {
        int mine = sc[tid];
        int up   = (tid >= d) ? sc[tid - d] : 0;
        __syncthreads();
        sc[tid] = mine + up;
        __syncthreads();
    }
    int excl = sc[tid] - v;

    int node = (b << BSH) + tid;
    if (node < n) {
        ptr[node]  = bstart + excl;
        dinv[node] = rsqrtf(1.0f + fs[tid]);
    }
    cnt[tid] = excl;          // reuse as local offsets
    __syncthreads();

    // pass 2: scatter into final CSR (bucket region is L2-resident)
    for (int j = bstart + tid; j < bend; j += 512) {
        int c = (int)ecol[j];
        int r = atomicAdd(&cur2[c], 1);
        csr[bstart + cnt[c] + r] = ebuf[j];
    }
    if (b == 0 && tid == 0) ptr[n] = e;
}

// W[128][M] f32 row-major -> bf16 fragment order (one thread per fragment)
__global__ void k_wfrag(const float* __restrict__ W, uint4* __restrict__ Wf, int M) {
    int t = blockIdx.x * 256 + threadIdx.x;
    if (t >= M * 16) return;
    int l  = t & 63;
    int ks = (t >> 6) & 3;
    int nt = t >> 8;
    int kbase = ks * 32 + (l >> 4) * 8;
    int colj  = nt * 16 + (l & 15);
    float v[8];
#pragma unroll
    for (int j = 0; j < 8; ++j) v[j] = W[(kbase + j) * M + colj];
    uint4 o;
    o.x = pack2(v[0], v[1]);
    o.y = pack2(v[2], v[3]);
    o.z = pack2(v[4], v[5]);
    o.w = pack2(v[6], v[7]);
    Wf[t] = o;
}

// H[n,M](bf16) = X'[n,128] @ W[128,M] via 16x16x32 bf16 MFMA.
// BN=false: X is f32.  BN=true: X is bf16, X' = relu(X*scale+shift).
template<int M, bool BN>
__global__ __launch_bounds__(256)
void k_mfma(const void* __restrict__ Xv, const uint4* __restrict__ Wf,
            const float* __restrict__ scale, const float* __restrict__ shift,
            ushort* __restrict__ H, int n)
{
    constexpr int NT = M / 16;
    const int l = threadIdx.x & 63;
    const int w = threadIdx.x >> 6;
    const int rowbase = blockIdx.x * 64 + w * 16;
    const int arow = rowbase + (l & 15);
    const bool rv = arow < n;
    const int koff = (l >> 4) * 8;

    f32x4 acc[NT];
#pragma unroll
    for (int t = 0; t < NT; ++t) acc[t] = (f32x4){0.f, 0.f, 0.f, 0.f};

#pragma unroll
    for (int ks = 0; ks < 4; ++ks) {
        U16 ua;
        if (BN) {
            const ushort* xr = (const ushort*)Xv + (size_t)arow * 128 + koff;
            U16 xa; xa.u = make_uint4(0, 0, 0, 0);
            if (rv) xa.u = *(const uint4*)(xr + ks * 32);
            int k0 = ks * 32 + koff;
            float4 sc0 = *(const float4*)(scale + k0);
            float4 sc1 = *(const float4*)(scale + k0 + 4);
            float4 sh0 = *(const float4*)(shift + k0);
            float4 sh1 = *(const float4*)(shift + k0 + 4);
            float a[8];
            a[0] = fmaxf(0.f, fmaf(bf2f((ushort)(xa.u.x)),       sc0.x, sh0.x));
            a[1] = fmaxf(0.f, fmaf(bf2f((ushort)(xa.u.x >> 16)), sc0.y, sh0.y));
            a[2] = fmaxf(0.f, fmaf(bf2f((ushort)(xa.u.y)),       sc0.z, sh0.z));
            a[3] = fmaxf(0.f, fmaf(bf2f((ushort)(xa.u.y >> 16)), sc0.w, sh0.w));
            a[4] = fmaxf(0.f, fmaf(bf2f((ushort)(xa.u.z)),       sc1.x, sh1.x));
            a[5] = fmaxf(0.f, fmaf(bf2f((ushort)(xa.u.z >> 16)), sc1.y, sh1.y));
            a[6] = fmaxf(0.f, fmaf(bf2f((ushort)(xa.u.w)),       sc1.z, sh1.z));
            a[7] = fmaxf(0.f, fmaf(bf2f((ushort)(xa.u.w >> 16)), sc1.w, sh1.w));
            ua.u.x = pack2(a[0], a[1]);
            ua.u.y = pack2(a[2], a[3]);
            ua.u.z = pack2(a[4], a[5]);
            ua.u.w = pack2(a[6], a[7]);
        } else {
            const float* xr = (const float*)Xv + (size_t)arow * 128 + koff;
            float4 a0 = make_float4(0.f, 0.f, 0.f, 0.f);
            float4 a1 = a0;
            if (rv) {
                a0 = *(const float4*)(xr + ks * 32);
                a1 = *(const float4*)(xr + ks * 32 + 4);
            }
            ua.u.x = pack2(a0.x, a0.y);
            ua.u.y = pack2(a0.z, a0.w);
            ua.u.z = pack2(a1.x, a1.y);
            ua.u.w = pack2(a1.z, a1.w);
        }
#pragma unroll
        for (int nt = 0; nt < NT; ++nt) {
            U16 ub;
            ub.u = Wf[(nt * 4 + ks) * 64 + l];
            acc[nt] = __builtin_amdgcn_mfma_f32_16x16x32_bf16(ua.b, ub.b, acc[nt], 0, 0, 0);
        }
    }

    // epilogue: transpose through padded LDS, then coalesced 16B stores.
    __shared__ __align__(16) ushort lds[4][16][M + 8];
#pragma unroll
    for (int nt = 0; nt < NT; ++nt)
#pragma unroll
        for (int r = 0; r < 4; ++r)
            lds[w][(l >> 4) * 4 + r][nt * 16 + (l & 15)] = f2bf(acc[nt][r]);
    __syncthreads();

    constexpr int LPR = M / 8;
    constexpr int RPP = 64 / LPR;
#pragma unroll
    for (int it = 0; it < 16 / RPP; ++it) {
        int rl = it * RPP + (l / LPR);
        int gr = rowbase + rl;
        if (gr < n)
            *(uint4*)(H + (size_t)gr * M + (l % LPR) * 8) =
                *(const uint4*)&lds[w][rl][(l % LPR) * 8];
    }
}

// layer-1 gather, 16-lane group per node (4 nodes/wave), bf16 in/out
__global__ __launch_bounds__(256)
void k_gather1(const int* __restrict__ ptr, const int2* __restrict__ csr,
               const ushort* __restrict__ h, const float* __restrict__ dinv,
               const float* __restrict__ bias, ushort* __restrict__ out, int n)
{
    int lane = threadIdx.x & 15;
    int node = (blockIdx.x * 256 + threadIdx.x) >> 4;
    if (node >= n) return;
    int p0 = ptr[node], p1 = ptr[node + 1];
    float di = dinv[node];
    float s  = di * di;

    U16 hv; hv.u = *(const uint4*)(h + (size_t)node * 128 + lane * 8);
    float4 b0 = *(const float4*)(bias + lane * 8);
    float4 b1v = *(const float4*)(bias + lane * 8 + 4);
    float acc[8];
    acc[0] = fmaf(bf2f((ushort)(hv.u.x)),       s, b0.x);
    acc[1] = fmaf(bf2f((ushort)(hv.u.x >> 16)), s, b0.y);
    acc[2] = fmaf(bf2f((ushort)(hv.u.y)),       s, b0.z);
    acc[3] = fmaf(bf2f((ushort)(hv.u.y >> 16)), s, b0.w);
    acc[4] = fmaf(bf2f((ushort)(hv.u.z)),       s, b1v.x);
    acc[5] = fmaf(bf2f((ushort)(hv.u.z >> 16)), s, b1v.y);
    acc[6] = fmaf(bf2f((ushort)(hv.u.w)),       s, b1v.z);
    acc[7] = fmaf(bf2f((ushort)(hv.u.w >> 16)), s, b1v.w);

#pragma unroll 4
    for (int j = p0; j < p1; ++j) {
        int2 pr = csr[j];
        float w = __int_as_float(pr.y) * di * dinv[pr.x];
        U16 v; v.u = *(const uint4*)(h + (size_t)pr.x * 128 + lane * 8);
        acc[0] = fmaf(bf2f((ushort)(v.u.x)),       w, acc[0]);
        acc[1] = fmaf(bf2f((ushort)(v.u.x >> 16)), w, acc[1]);
        acc[2] = fmaf(bf2f((ushort)(v.u.y)),       w, acc[2]);
        acc[3] = fmaf(bf2f((ushort)(v.u.y >> 16)), w, acc[3]);
        acc[4] = fmaf(bf2f((ushort)(v.u.z)),       w, acc[4]);
        acc[5] = fmaf(bf2f((ushort)(v.u.z >> 16)), w, acc[5]);
        acc[6] = fmaf(bf2f((ushort)(v.u.w)),       w, acc[6]);
        acc[7] = fmaf(bf2f((ushort)(v.u.w >> 16)), w, acc[7]);
    }

    U16 o;
    o.u.x = pack2(acc[0], acc[1]);
    o.u.y = pack2(acc[2], acc[3]);
    o.u.z = pack2(acc[4], acc[5]);
    o.u.w = pack2(acc[6], acc[7]);
    *(uint4*)(out + (size_t)node * 128 + lane * 8) = o.u;
}

// layer-2 gather + fused log_softmax, 8-lane group per node (8 nodes/wave)
__global__ __launch_bounds__(256)
void k_gather2(const int* __restrict__ ptr, const int2* __restrict__ csr,
               const ushort* __restrict__ h, const float* __restrict__ dinv,
               const float* __restrict__ bias, float* __restrict__ out, int n)
{
    int lane = threadIdx.x & 7;
    int node = (blockIdx.x * 256 + threadIdx.x) >> 3;
    if (node >= n) return;
    int p0 = ptr[node], p1 = ptr[node + 1];
    float di = dinv[node];
    float s  = di * di;

    U16 hv; hv.u = *(const uint4*)(h + (size_t)node * 64 + lane * 8);
    float4 b0 = *(const float4*)(bias + lane * 8);
    float4 b1v = *(const float4*)(bias + lane * 8 + 4);
    float acc[8];
    acc[0] = fmaf(bf2f((ushort)(hv.u.x)),       s, b0.x);
    acc[1] = fmaf(bf2f((ushort)(hv.u.x >> 16)), s, b0.y);
    acc[2] = fmaf(bf2f((ushort)(hv.u.y)),       s, b0.z);
    acc[3] = fmaf(bf2f((ushort)(hv.u.y >> 16)), s, b0.w);
    acc[4] = fmaf(bf2f((ushort)(hv.u.z)),       s, b1v.x);
    acc[5] = fmaf(bf2f((ushort)(hv.u.z >> 16)), s, b1v.y);
    acc[6] = fmaf(bf2f((ushort)(hv.u.w)),       s, b1v.z);
    acc[7] = fmaf(bf2f((ushort)(hv.u.w >> 16)), s, b1v.w);

#pragma unroll 4
    for (int j = p0; j < p1; ++j) {
        int2 pr = csr[j];
        float w = __int_as_float(pr.y) * di * dinv[pr.x];
        U16 v; v.u = *(const uint4*)(h + (size_t)pr.x * 64 + lane * 8);
        acc[0] = fmaf(bf2f((ushort)(v.u.x)),       w, acc[0]);
        acc[1] = fmaf(bf2f((ushort)(v.u.x >> 16)), w, acc[1]);
        acc[2] = fmaf(bf2f((ushort)(v.u.y)),       w, acc[2]);
        acc[3] = fmaf(bf2f((ushort)(v.u.y >> 16)), w, acc[3]);
        acc[4] = fmaf(bf2f((ushort)(v.u.z)),       w, acc[4]);
        acc[5] = fmaf(bf2f((ushort)(v.u.z >> 16)), w, acc[5]);
        acc[6] = fmaf(bf2f((ushort)(v.u.w)),       w, acc[6]);
        acc[7] = fmaf(bf2f((ushort)(v.u.w >> 16)), w, acc[7]);
    }

    float m = acc[0];
#pragma unroll
    for (int k = 1; k < 8; ++k) m = fmaxf(m, acc[k]);
#pragma unroll
    for (int off = 1; off < 8; off <<= 1) m = fmaxf(m, __shfl_xor(m, off, 64));
    float sum = 0.f;
#pragma unroll
    for (int k = 0; k < 8; ++k) sum += expf(acc[k] - m);
#pragma unroll
    for (int off = 1; off < 8; off <<= 1) sum += __shfl_xor(sum, off, 64);
    float lse = m + logf(sum);

    float* orow = out + (size_t)node * 64 + lane * 8;
    *(float4*)(orow)     = make_float4(acc[0] - lse, acc[1] - lse, acc[2] - lse, acc[3] - lse);
    *(float4*)(orow + 4) = make_float4(acc[4] - lse, acc[5] - lse, acc[6] - lse, acc[7] - lse);
}

// per-feature sum & sumsq over nodes; a is bf16[n][128]
__global__ __launch_bounds__(256)
void k_bn_stats(const ushort* __restrict__ a, float* __restrict__ sums,
                float* __restrict__ sumsq, int n)
{
    int fp = threadIdx.x & 63;
    int rg = threadIdx.x >> 6;
    float s0 = 0.f, q0 = 0.f, s1 = 0.f, q1 = 0.f;
    for (int r = blockIdx.x * 4 + rg; r < n; r += gridDim.x * 4) {
        uint v = *(const uint*)(a + (size_t)r * 128 + fp * 2);
        float x0 = bf2f((ushort)v), x1 = bf2f((ushort)(v >> 16));
        s0 += x0; q0 += x0 * x0;
        s1 += x1; q1 += x1 * x1;
    }
    __shared__ float l0[256], l1[256], l2[256], l3[256];
    l0[threadIdx.x] = s0; l1[threadIdx.x] = q0;
    l2[threadIdx.x] = s1; l3[threadIdx.x] = q1;
    __syncthreads();
    if (rg == 0) {
        float S0 = l0[fp] + l0[fp + 64] + l0[fp + 128] + l0[fp + 192];
        float Q0 = l1[fp] + l1[fp + 64] + l1[fp + 128] + l1[fp + 192];
        float S1 = l2[fp] + l2[fp + 64] + l2[fp + 128] + l2[fp + 192];
        float Q1 = l3[fp] + l3[fp + 64] + l3[fp + 128] + l3[fp + 192];
        atomAddF(&sums[fp * 2],      S0);
        atomAddF(&sumsq[fp * 2],     Q0);
        atomAddF(&sums[fp * 2 + 1],  S1);
        atomAddF(&sumsq[fp * 2 + 1], Q1);
    }
}

__global__ void k_bn_final(const float* __restrict__ bn, const float* __restrict__ gamma,
                           const float* __restrict__ beta, float* __restrict__ scale,
                           float* __restrict__ shift, int n)
{
    int f = threadIdx.x;
    if (f < 128) {
        float inv_n = 1.0f / (float)n;
        float mu  = bn[f] * inv_n;
        float var = bn[128 + f] * inv_n - mu * mu;
        float rstd = rsqrtf(var + 1e-5f);
        float sc = gamma[f] * rstd;
        scale[f] = sc;
        shift[f] = beta[f] - mu * sc;
    }
}

extern "C" void kernel_launch(void* const* d_in, const int* in_sizes, int n_in,
                              void* d_out, int out_size, void* d_ws, size_t ws_size,
                              hipStream_t stream)
{
    const float* x     = (const float*)d_in[0];
    const int*   ei    = (const int*)  d_in[1];
    const float* ew    = (const float*)d_in[2];
    const float* W1    = (const float*)d_in[3];
    const float* b1    = (const float*)d_in[4];
    const float* gamma = (const float*)d_in[5];
    const float* beta  = (const float*)d_in[6];
    const float* W2    = (const float*)d_in[7];
    const float* b2    = (const float*)d_in[8];

    const int n = in_sizes[0] / 128;   // 100000
    const int e = in_sizes[2];         // 1600000
    const int* row = ei;               // edge_index[0]  (source)
    const int* col = ei + e;           // edge_index[1]  (target)

    const int PB  = (e + EPB - 1) / EPB;          // 391 P1/P3 blocks
    const int NB  = (n + (1 << BSH) - 1) >> BSH;  // 196 buckets
    const int tot = NB * PB;                      // 76636 scan elements

    // workspace layout (4-byte units)
    float* ws    = (float*)d_ws;
    size_t off   = 0;
    float* dinv  = ws + off; off += n;
    ushort* h1   = (ushort*)(ws + off); off += (size_t)n * 64;  // n*128 bf16
    ushort* agg1 = (ushort*)(ws + off); off += (size_t)n * 64;  // n*128 bf16
    float* bn    = ws + off; off += 256;
    float* scale = ws + off; off += 128;
    float* shift = ws + off; off += 128;
    int*   ptr   = (int*)(ws + off); off += (size_t)(n + 1);
    int*   bsum  = (int*)(ws + off); off += 1024;
    int*   ghist = (int*)(ws + off); off += (size_t)PB * 256;
    int*   goff  = (int*)(ws + off); off += (size_t)(tot + 1);
    off = (off + 3) & ~(size_t)3;       // 16-byte align
    uint4* w1f   = (uint4*)(ws + off); off += 8192;  // 128*128 bf16 = 2048 uint4
    uint4* w2f   = (uint4*)(ws + off); off += 4096;  // 128*64  bf16 = 1024 uint4
    int2*  ebuf  = (int2*)(ws + off); off += (size_t)e * 2;
    int2*  csr   = (int2*)(ws + off); off += (size_t)e * 2;
    ushort* ecol = (ushort*)(ws + off); off += (size_t)(e + 1) / 2;
    ushort* h2   = h1;                  // h1 dead after k_gather1
    float* outp  = (float*)d_out;

    const int nb_qpn = (n + 15) / 16;   // 16-lane-group-per-node
    const int nb_opn = (n + 31) / 32;   // 8-lane-group-per-node
    const int nb_mf  = (n + 63) / 64;   // MFMA gemm: 64 rows/block
    const int nblk_scan = (tot + 1023) / 1024;   // 75 <= 1024

    // W fragment swizzle (no deps)
    k_wfrag<<<8, 256, 0, stream>>>(W1, w1f, 128);
    k_wfrag<<<4, 256, 0, stream>>>(W2, w2f, 64);

    // CSR build, atomic-free at global scope:
    k_p1<<<PB, 256, 0, stream>>>(col, ghist, e, PB);
    k_scanA<<<nblk_scan, 256, 0, stream>>>(ghist, bsum, tot);
    k_scanB<<<1, 1024, 0, stream>>>(bsum, bn, nblk_scan);
    k_scanC<<<nblk_scan, 256, 0, stream>>>(ghist, bsum, goff, tot);
    k_p3<<<PB, 256, 0, stream>>>(row, col, ew, goff, ebuf, ecol, e, PB);
    k_p4<<<NB, 512, 0, stream>>>(goff, ebuf, ecol, csr, ptr, dinv, n, e, PB, NB);

    // ---- layer 1: h1 = x @ W1 (bf16, MFMA) ; agg1 = gather(h1) + b1 (bf16) ----
    k_mfma<128, false><<<nb_mf, 256, 0, stream>>>(x, w1f, nullptr, nullptr, h1, n);
    k_gather1<<<nb_qpn, 256, 0, stream>>>(ptr, csr, h1, dinv, b1, agg1, n);

    // ---- batchnorm stats -> scale/shift ----
    k_bn_stats<<<256, 256, 0, stream>>>(agg1, bn, bn + 128, n);
    k_bn_final<<<1, 128, 0, stream>>>(bn, gamma, beta, scale, shift, n);

    // ---- layer 2: h2 = relu(bn(agg1)) @ W2 (bf16, MFMA) ; out + lsm ----
    k_mfma<64, true><<<nb_mf, 256, 0, stream>>>(agg1, w2f, scale, shift, h2, n);
    k_gather2<<<nb_opn, 256, 0, stream>>>(ptr, csr, h2, dinv, b2, outp, n);
}

// Round 13
// 241.431 us; speedup vs baseline: 1.2495x; 1.0479x over previous
//
#include <hip/hip_runtime.h>
#include <math.h>

// ---------------------------------------------------------------------------
// TrafficGNN: 2-layer GCN + BN + ReLU + log_softmax.
// Round 13: (a) k_gather1 -> 8-lane-group-per-node (8 nodes/wave, 2 uint4
// loads per lane per edge = 4x MLP vs R12) — tests latency-vs-L3-BW bound;
// (b) P3 staging packs colLow(9b) into src's high bits (src < 2^17) —
// ecol array eliminated, one fewer scattered store stream.
// ---------------------------------------------------------------------------

typedef unsigned int   uint;
typedef unsigned short ushort;
typedef __bf16 bf16x8 __attribute__((ext_vector_type(8)));
typedef float  f32x4  __attribute__((ext_vector_type(4)));

#define EPB  4096      // edges per P1/P3 block
#define BSH  9         // 512 nodes per bucket; requires n < 2^17 for packing

union U16 { uint4 u; bf16x8 b; };

__device__ __forceinline__ void atomAddF(float* p, float v) {
    __hip_atomic_fetch_add(p, v, __ATOMIC_RELAXED, __HIP_MEMORY_SCOPE_AGENT);
}

__device__ __forceinline__ ushort f2bf(float f) {
    uint u = __float_as_uint(f);
    u += 0x7FFFu + ((u >> 16) & 1u);
    return (ushort)(u >> 16);
}
__device__ __forceinline__ float bf2f(ushort h) {
    return __uint_as_float(((uint)h) << 16);
}
__device__ __forceinline__ uint pack2(float f0, float f1) {
    return (uint)f2bf(f0) | ((uint)f2bf(f1) << 16);
}
// acc[0..7] += bf16x8(v) * w
__device__ __forceinline__ void fma8(float* acc, uint4 v, float w) {
    acc[0] = fmaf(bf2f((ushort)(v.x)),       w, acc[0]);
    acc[1] = fmaf(bf2f((ushort)(v.x >> 16)), w, acc[1]);
    acc[2] = fmaf(bf2f((ushort)(v.y)),       w, acc[2]);
    acc[3] = fmaf(bf2f((ushort)(v.y >> 16)), w, acc[3]);
    acc[4] = fmaf(bf2f((ushort)(v.z)),       w, acc[4]);
    acc[5] = fmaf(bf2f((ushort)(v.z >> 16)), w, acc[5]);
    acc[6] = fmaf(bf2f((ushort)(v.w)),       w, acc[6]);
    acc[7] = fmaf(bf2f((ushort)(v.w >> 16)), w, acc[7]);
}

// ---- P1: per-block LDS histogram over buckets (col>>BSH) ----
__global__ __launch_bounds__(256)
void k_p1(const int* __restrict__ col, int* __restrict__ ghist,
          int e, int PB) {
    __shared__ int lh[256];
    lh[threadIdx.x] = 0;
    __syncthreads();
    int base = blockIdx.x * EPB;
    int end  = base + EPB; if (end > e) end = e;
    for (int j = base + threadIdx.x; j < end; j += 256)
        atomicAdd(&lh[col[j] >> BSH], 1);
    __syncthreads();
    ghist[threadIdx.x * PB + blockIdx.x] = lh[threadIdx.x];   // bucket-major
}

// ---- linear exclusive scan over tot = NB*PB elements ----
__global__ __launch_bounds__(256)
void k_scanA(const int* __restrict__ v, int* __restrict__ bsum, int tot) {
    __shared__ int ls[256];
    int base = blockIdx.x * 1024 + threadIdx.x * 4;
    int s = 0;
#pragma unroll
    for (int k = 0; k < 4; ++k) { int i = base + k; if (i < tot) s += v[i]; }
    ls[threadIdx.x] = s;
    __syncthreads();
    for (int d = 128; d > 0; d >>= 1) {
        if (threadIdx.x < d) ls[threadIdx.x] += ls[threadIdx.x + d];
        __syncthreads();
    }
    if (threadIdx.x == 0) bsum[blockIdx.x] = ls[0];
}

// parallel exclusive scan of block sums; also zeroes BN accumulators
__global__ __launch_bounds__(1024)
void k_scanB(int* __restrict__ bsum, float* __restrict__ bn, int nblk) {
    __shared__ int ls[1024];
    int t = threadIdx.x;
    if (t < 256) bn[t] = 0.0f;
    int v = (t < nblk) ? bsum[t] : 0;
    ls[t] = v;
    __syncthreads();
    for (int d = 1; d < 1024; d <<= 1) {
        int mine = ls[t];
        int up   = (t >= d) ? ls[t - d] : 0;
        __syncthreads();
        ls[t] = mine + up;
        __syncthreads();
    }
    if (t < nblk) bsum[t] = ls[t] - v;   // exclusive
}

__global__ __launch_bounds__(256)
void k_scanC(const int* __restrict__ v, const int* __restrict__ bsum,
             int* __restrict__ gout, int tot) {
    __shared__ int ls[256];
    int base = blockIdx.x * 1024 + threadIdx.x * 4;
    int w[4];
#pragma unroll
    for (int k = 0; k < 4; ++k) { int i = base + k; w[k] = (i < tot) ? v[i] : 0; }
    int t = w[0] + w[1] + w[2] + w[3];
    ls[threadIdx.x] = t;
    __syncthreads();
    for (int d = 1; d < 256; d <<= 1) {
        int mine = ls[threadIdx.x];
        int up   = (threadIdx.x >= d) ? ls[threadIdx.x - d] : 0;
        __syncthreads();
        ls[threadIdx.x] = mine + up;
        __syncthreads();
    }
    int off = bsum[blockIdx.x] + ls[threadIdx.x] - t;   // exclusive
    int pf = 0;
#pragma unroll
    for (int k = 0; k < 4; ++k) {
        int i = base + k;
        if (i < tot) gout[i] = off + pf;
        pf += w[k];
    }
}

// ---- P3: scatter edges into bucket-partitioned staging (LDS ranks) ----
// record: x = src | (colLow << 17)   (n < 2^17), y = raw ew bits
__global__ __launch_bounds__(256)
void k_p3(const int* __restrict__ row, const int* __restrict__ col,
          const float* __restrict__ ew, const int* __restrict__ goff,
          int2* __restrict__ ebuf, int e, int PB) {
    __shared__ int cur[256];
    cur[threadIdx.x] = 0;
    __syncthreads();
    int blk  = blockIdx.x;
    int base = blk * EPB;
    int end  = base + EPB; if (end > e) end = e;
    for (int j = base + threadIdx.x; j < end; j += 256) {
        int c = col[j];
        int b = c >> BSH;
        int r = atomicAdd(&cur[b], 1);
        int pos = goff[b * PB + blk] + r;
        ebuf[pos] = make_int2(row[j] | ((c & ((1 << BSH) - 1)) << 17),
                              __float_as_int(ew[j]));
    }
}

// ---- P4: per-bucket CSR build + dinv (one block of 512 per bucket) ----
__global__ __launch_bounds__(512)
void k_p4(const int* __restrict__ goff, const int2* __restrict__ ebuf,
          int2* __restrict__ csr, int* __restrict__ ptr,
          float* __restrict__ dinv, int n, int e, int PB, int NB) {
    __shared__ int   cnt[512];
    __shared__ float fs[512];
    __shared__ int   cur2[512];
    __shared__ int   sc[512];
    int tid = threadIdx.x;
    int b   = blockIdx.x;
    int bstart = goff[b * PB];
    int bend   = (b == NB - 1) ? e : goff[(b + 1) * PB];

    cnt[tid] = 0; fs[tid] = 0.f; cur2[tid] = 0;
    __syncthreads();

    // pass 1: per-node counts + edge-weight sums
    for (int j = bstart + tid; j < bend; j += 512) {
        int2 eb = ebuf[j];
        int c = (eb.x >> 17) & 511;
        atomicAdd(&cnt[c], 1);
        atomicAdd(&fs[c], __int_as_float(eb.y));
    }
    __syncthreads();

    // exclusive scan of cnt[512]
    int v = cnt[tid];
    sc[tid] = v;
    __syncthreads();
    for (int d = 1; d < 512; d <<= 1) {
        int mine = sc[tid];
        int up   = (tid >= d) ? sc[tid - d] : 0;
        __syncthreads();
        sc[tid] = mine + up;
        __syncthreads();
    }
    int excl = sc[tid] - v;

    int node = (b << BSH) + tid;
    if (node < n) {
        ptr[node]  = bstart + excl;
        dinv[node] = rsqrtf(1.0f + fs[tid]);
    }
    cnt[tid] = excl;          // reuse as local offsets
    __syncthreads();

    // pass 2: scatter into final CSR (bucket region is L2-resident)
    for (int j = bstart + tid; j < bend; j += 512) {
        int2 eb = ebuf[j];
        int c = (eb.x >> 17) & 511;
        int r = atomicAdd(&cur2[c], 1);
        csr[bstart + cnt[c] + r] = make_int2(eb.x & 0x1FFFF, eb.y);
    }
    if (b == 0 && tid == 0) ptr[n] = e;
}

// W[128][M] f32 row-major -> bf16 fragment order (one thread per fragment)
__global__ void k_wfrag(const float* __restrict__ W, uint4* __restrict__ Wf, int M) {
    int t = blockIdx.x * 256 + threadIdx.x;
    if (t >= M * 16) return;
    int l  = t & 63;
    int ks = (t >> 6) & 3;
    int nt = t >> 8;
    int kbase = ks * 32 + (l >> 4) * 8;
    int colj  = nt * 16 + (l & 15);
    float v[8];
#pragma unroll
    for (int j = 0; j < 8; ++j) v[j] = W[(kbase + j) * M + colj];
    uint4 o;
    o.x = pack2(v[0], v[1]);
    o.y = pack2(v[2], v[3]);
    o.z = pack2(v[4], v[5]);
    o.w = pack2(v[6], v[7]);
    Wf[t] = o;
}

// H[n,M](bf16) = X'[n,128] @ W[128,M] via 16x16x32 bf16 MFMA.
// BN=false: X is f32.  BN=true: X is bf16, X' = relu(X*scale+shift).
template<int M, bool BN>
__global__ __launch_bounds__(256)
void k_mfma(const void* __restrict__ Xv, const uint4* __restrict__ Wf,
            const float* __restrict__ scale, const float* __restrict__ shift,
            ushort* __restrict__ H, int n)
{
    constexpr int NT = M / 16;
    const int l = threadIdx.x & 63;
    const int w = threadIdx.x >> 6;
    const int rowbase = blockIdx.x * 64 + w * 16;
    const int arow = rowbase + (l & 15);
    const bool rv = arow < n;
    const int koff = (l >> 4) * 8;

    f32x4 acc[NT];
#pragma unroll
    for (int t = 0; t < NT; ++t) acc[t] = (f32x4){0.f, 0.f, 0.f, 0.f};

#pragma unroll
    for (int ks = 0; ks < 4; ++ks) {
        U16 ua;
        if (BN) {
            const ushort* xr = (const ushort*)Xv + (size_t)arow * 128 + koff;
            U16 xa; xa.u = make_uint4(0, 0, 0, 0);
            if (rv) xa.u = *(const uint4*)(xr + ks * 32);
            int k0 = ks * 32 + koff;
            float4 sc0 = *(const float4*)(scale + k0);
            float4 sc1 = *(const float4*)(scale + k0 + 4);
            float4 sh0 = *(const float4*)(shift + k0);
            float4 sh1 = *(const float4*)(shift + k0 + 4);
            float a[8];
            a[0] = fmaxf(0.f, fmaf(bf2f((ushort)(xa.u.x)),       sc0.x, sh0.x));
            a[1] = fmaxf(0.f, fmaf(bf2f((ushort)(xa.u.x >> 16)), sc0.y, sh0.y));
            a[2] = fmaxf(0.f, fmaf(bf2f((ushort)(xa.u.y)),       sc0.z, sh0.z));
            a[3] = fmaxf(0.f, fmaf(bf2f((ushort)(xa.u.y >> 16)), sc0.w, sh0.w));
            a[4] = fmaxf(0.f, fmaf(bf2f((ushort)(xa.u.z)),       sc1.x, sh1.x));
            a[5] = fmaxf(0.f, fmaf(bf2f((ushort)(xa.u.z >> 16)), sc1.y, sh1.y));
            a[6] = fmaxf(0.f, fmaf(bf2f((ushort)(xa.u.w)),       sc1.z, sh1.z));
            a[7] = fmaxf(0.f, fmaf(bf2f((ushort)(xa.u.w >> 16)), sc1.w, sh1.w));
            ua.u.x = pack2(a[0], a[1]);
            ua.u.y = pack2(a[2], a[3]);
            ua.u.z = pack2(a[4], a[5]);
            ua.u.w = pack2(a[6], a[7]);
        } else {
            const float* xr = (const float*)Xv + (size_t)arow * 128 + koff;
            float4 a0 = make_float4(0.f, 0.f, 0.f, 0.f);
            float4 a1 = a0;
            if (rv) {
                a0 = *(const float4*)(xr + ks * 32);
                a1 = *(const float4*)(xr + ks * 32 + 4);
            }
            ua.u.x = pack2(a0.x, a0.y);
            ua.u.y = pack2(a0.z, a0.w);
            ua.u.z = pack2(a1.x, a1.y);
            ua.u.w = pack2(a1.z, a1.w);
        }
#pragma unroll
        for (int nt = 0; nt < NT; ++nt) {
            U16 ub;
            ub.u = Wf[(nt * 4 + ks) * 64 + l];
            acc[nt] = __builtin_amdgcn_mfma_f32_16x16x32_bf16(ua.b, ub.b, acc[nt], 0, 0, 0);
        }
    }

    // epilogue: transpose through padded LDS, then coalesced 16B stores.
    __shared__ __align__(16) ushort lds[4][16][M + 8];
#pragma unroll
    for (int nt = 0; nt < NT; ++nt)
#pragma unroll
        for (int r = 0; r < 4; ++r)
            lds[w][(l >> 4) * 4 + r][nt * 16 + (l & 15)] = f2bf(acc[nt][r]);
    __syncthreads();

    constexpr int LPR = M / 8;
    constexpr int RPP = 64 / LPR;
#pragma unroll
    for (int it = 0; it < 16 / RPP; ++it) {
        int rl = it * RPP + (l / LPR);
        int gr = rowbase + rl;
        if (gr < n)
            *(uint4*)(H + (size_t)gr * M + (l % LPR) * 8) =
                *(const uint4*)&lds[w][rl][(l % LPR) * 8];
    }
}

// layer-1 gather, 8-lane group per node (8 nodes/wave, 2 uint4 loads/edge):
// out bf16 = b1 + h[i]*dinv^2 + sum h[src]*(ew*dinv[src]*di); h bf16[n][128]
__global__ __launch_bounds__(256)
void k_gather1(const int* __restrict__ ptr, const int2* __restrict__ csr,
               const ushort* __restrict__ h, const float* __restrict__ dinv,
               const float* __restrict__ bias, ushort* __restrict__ out, int n)
{
    int lane = threadIdx.x & 7;
    int node = (blockIdx.x * 256 + threadIdx.x) >> 3;
    if (node >= n) return;
    int p0 = ptr[node], p1 = ptr[node + 1];
    float di = dinv[node];
    float s  = di * di;

    const ushort* hrow = h + (size_t)node * 128 + lane * 16;
    U16 h0, h1v; h0.u = *(const uint4*)hrow; h1v.u = *(const uint4*)(hrow + 8);
    float acc[16];
    {
        const float* bp = bias + lane * 16;
#pragma unroll
        for (int k = 0; k < 16; ++k) acc[k] = bp[k];
        fma8(acc,     h0.u,  s);
        fma8(acc + 8, h1v.u, s);
    }

#pragma unroll 4
    for (int j = p0; j < p1; ++j) {
        int2 pr = csr[j];
        float w = __int_as_float(pr.y) * di * dinv[pr.x];
        const ushort* sr = h + (size_t)pr.x * 128 + lane * 16;
        U16 v0, v1; v0.u = *(const uint4*)sr; v1.u = *(const uint4*)(sr + 8);
        fma8(acc,     v0.u, w);
        fma8(acc + 8, v1.u, w);
    }

    U16 o0, o1;
    o0.u.x = pack2(acc[0],  acc[1]);
    o0.u.y = pack2(acc[2],  acc[3]);
    o0.u.z = pack2(acc[4],  acc[5]);
    o0.u.w = pack2(acc[6],  acc[7]);
    o1.u.x = pack2(acc[8],  acc[9]);
    o1.u.y = pack2(acc[10], acc[11]);
    o1.u.z = pack2(acc[12], acc[13]);
    o1.u.w = pack2(acc[14], acc[15]);
    ushort* orow = out + (size_t)node * 128 + lane * 16;
    *(uint4*)(orow)     = o0.u;
    *(uint4*)(orow + 8) = o1.u;
}

// layer-2 gather + fused log_softmax, 8-lane group per node (8 nodes/wave)
__global__ __launch_bounds__(256)
void k_gather2(const int* __restrict__ ptr, const int2* __restrict__ csr,
               const ushort* __restrict__ h, const float* __restrict__ dinv,
               const float* __restrict__ bias, float* __restrict__ out, int n)
{
    int lane = threadIdx.x & 7;
    int node = (blockIdx.x * 256 + threadIdx.x) >> 3;
    if (node >= n) return;
    int p0 = ptr[node], p1 = ptr[node + 1];
    float di = dinv[node];
    float s  = di * di;

    U16 hv; hv.u = *(const uint4*)(h + (size_t)node * 64 + lane * 8);
    float acc[8];
    {
        const float* bp = bias + lane * 8;
#pragma unroll
        for (int k = 0; k < 8; ++k) acc[k] = bp[k];
        fma8(acc, hv.u, s);
    }

#pragma unroll 4
    for (int j = p0; j < p1; ++j) {
        int2 pr = csr[j];
        float w = __int_as_float(pr.y) * di * dinv[pr.x];
        U16 v; v.u = *(const uint4*)(h + (size_t)pr.x * 64 + lane * 8);
        fma8(acc, v.u, w);
    }

    float m = acc[0];
#pragma unroll
    for (int k = 1; k < 8; ++k) m = fmaxf(m, acc[k]);
#pragma unroll
    for (int off = 1; off < 8; off <<= 1) m = fmaxf(m, __shfl_xor(m, off, 64));
    float sum = 0.f;
#pragma unroll
    for (int k = 0; k < 8; ++k) sum += expf(acc[k] - m);
#pragma unroll
    for (int off = 1; off < 8; off <<= 1) sum += __shfl_xor(sum, off, 64);
    float lse = m + logf(sum);

    float* orow = out + (size_t)node * 64 + lane * 8;
    *(float4*)(orow)     = make_float4(acc[0] - lse, acc[1] - lse, acc[2] - lse, acc[3] - lse);
    *(float4*)(orow + 4) = make_float4(acc[4] - lse, acc[5] - lse, acc[6] - lse, acc[7] - lse);
}

// per-feature sum & sumsq over nodes; a is bf16[n][128]
__global__ __launch_bounds__(256)
void k_bn_stats(const ushort* __restrict__ a, float* __restrict__ sums,
                float* __restrict__ sumsq, int n)
{
    int fp = threadIdx.x & 63;
    int rg = threadIdx.x >> 6;
    float s0 = 0.f, q0 = 0.f, s1 = 0.f, q1 = 0.f;
    for (int r = blockIdx.x * 4 + rg; r < n; r += gridDim.x * 4) {
        uint v = *(const uint*)(a + (size_t)r * 128 + fp * 2);
        float x0 = bf2f((ushort)v), x1 = bf2f((ushort)(v >> 16));
        s0 += x0; q0 += x0 * x0;
        s1 += x1; q1 += x1 * x1;
    }
    __shared__ float l0[256], l1[256], l2[256], l3[256];
    l0[threadIdx.x] = s0; l1[threadIdx.x] = q0;
    l2[threadIdx.x] = s1; l3[threadIdx.x] = q1;
    __syncthreads();
    if (rg == 0) {
        float S0 = l0[fp] + l0[fp + 64] + l0[fp + 128] + l0[fp + 192];
        float Q0 = l1[fp] + l1[fp + 64] + l1[fp + 128] + l1[fp + 192];
        float S1 = l2[fp] + l2[fp + 64] + l2[fp + 128] + l2[fp + 192];
        float Q1 = l3[fp] + l3[fp + 64] + l3[fp + 128] + l3[fp + 192];
        atomAddF(&sums[fp * 2],      S0);
        atomAddF(&sumsq[fp * 2],     Q0);
        atomAddF(&sums[fp * 2 + 1],  S1);
        atomAddF(&sumsq[fp * 2 + 1], Q1);
    }
}

__global__ void k_bn_final(const float* __restrict__ bn, const float* __restrict__ gamma,
                           const float* __restrict__ beta, float* __restrict__ scale,
                           float* __restrict__ shift, int n)
{
    int f = threadIdx.x;
    if (f < 128) {
        float inv_n = 1.0f / (float)n;
        float mu  = bn[f] * inv_n;
        float var = bn[128 + f] * inv_n - mu * mu;
        float rstd = rsqrtf(var + 1e-5f);
        float sc = gamma[f] * rstd;
        scale[f] = sc;
        shift[f] = beta[f] - mu * sc;
    }
}

extern "C" void kernel_launch(void* const* d_in, const int* in_sizes, int n_in,
                              void* d_out, int out_size, void* d_ws, size_t ws_size,
                              hipStream_t stream)
{
    const float* x     = (const float*)d_in[0];
    const int*   ei    = (const int*)  d_in[1];
    const float* ew    = (const float*)d_in[2];
    const float* W1    = (const float*)d_in[3];
    const float* b1    = (const float*)d_in[4];
    const float* gamma = (const float*)d_in[5];
    const float* beta  = (const float*)d_in[6];
    const float* W2    = (const float*)d_in[7];
    const float* b2    = (const float*)d_in[8];

    const int n = in_sizes[0] / 128;   // 100000 (< 2^17, required by packing)
    const int e = in_sizes[2];         // 1600000
    const int* row = ei;               // edge_index[0]  (source)
    const int* col = ei + e;           // edge_index[1]  (target)

    const int PB  = (e + EPB - 1) / EPB;          // 391 P1/P3 blocks
    const int NB  = (n + (1 << BSH) - 1) >> BSH;  // 196 buckets
    const int tot = NB * PB;                      // 76636 scan elements

    // workspace layout (4-byte units)
    float* ws    = (float*)d_ws;
    size_t off   = 0;
    float* dinv  = ws + off; off += n;
    ushort* h1   = (ushort*)(ws + off); off += (size_t)n * 64;  // n*128 bf16
    ushort* agg1 = (ushort*)(ws + off); off += (size_t)n * 64;  // n*128 bf16
    float* bn    = ws + off; off += 256;
    float* scale = ws + off; off += 128;
    float* shift = ws + off; off += 128;
    int*   ptr   = (int*)(ws + off); off += (size_t)(n + 1);
    int*   bsum  = (int*)(ws + off); off += 1024;
    int*   ghist = (int*)(ws + off); off += (size_t)PB * 256;
    int*   goff  = (int*)(ws + off); off += (size_t)(tot + 1);
    off = (off + 3) & ~(size_t)3;       // 16-byte align
    uint4* w1f   = (uint4*)(ws + off); off += 8192;  // 128*128 bf16 = 2048 uint4
    uint4* w2f   = (uint4*)(ws + off); off += 4096;  // 128*64  bf16 = 1024 uint4
    int2*  ebuf  = (int2*)(ws + off); off += (size_t)e * 2;
    int2*  csr   = (int2*)(ws + off); off += (size_t)e * 2;
    ushort* h2   = h1;                  // h1 dead after k_gather1
    float* outp  = (float*)d_out;

    const int nb_opn = (n + 31) / 32;   // 8-lane-group-per-node
    const int nb_mf  = (n + 63) / 64;   // MFMA gemm: 64 rows/block
    const int nblk_scan = (tot + 1023) / 1024;   // 75 <= 1024

    // W fragment swizzle (no deps)
    k_wfrag<<<8, 256, 0, stream>>>(W1, w1f, 128);
    k_wfrag<<<4, 256, 0, stream>>>(W2, w2f, 64);

    // CSR build, atomic-free at global scope:
    k_p1<<<PB, 256, 0, stream>>>(col, ghist, e, PB);
    k_scanA<<<nblk_scan, 256, 0, stream>>>(ghist, bsum, tot);
    k_scanB<<<1, 1024, 0, stream>>>(bsum, bn, nblk_scan);
    k_scanC<<<nblk_scan, 256, 0, stream>>>(ghist, bsum, goff, tot);
    k_p3<<<PB, 256, 0, stream>>>(row, col, ew, goff, ebuf, e, PB);
    k_p4<<<NB, 512, 0, stream>>>(goff, ebuf, csr, ptr, dinv, n, e, PB, NB);

    // ---- layer 1: h1 = x @ W1 (bf16, MFMA) ; agg1 = gather(h1) + b1 (bf16) ----
    k_mfma<128, false><<<nb_mf, 256, 0, stream>>>(x, w1f, nullptr, nullptr, h1, n);
    k_gather1<<<nb_opn, 256, 0, stream>>>(ptr, csr, h1, dinv, b1, agg1, n);

    // ---- batchnorm stats -> scale/shift ----
    k_bn_stats<<<256, 256, 0, stream>>>(agg1, bn, bn + 128, n);
    k_bn_final<<<1, 128, 0, stream>>>(bn, gamma, beta, scale, shift, n);

    // ---- layer 2: h2 = relu(bn(agg1)) @ W2 (bf16, MFMA) ; out + lsm ----
    k_mfma<64, true><<<nb_mf, 256, 0, stream>>>(agg1, w2f, scale, shift, h2, n);
    k_gather2<<<nb_opn, 256, 0, stream>>>(ptr, csr, h2, dinv, b2, outp, n);
}